// Round 8
// baseline (747.650 us; speedup 1.0000x reference)
//
#include <hip/hip_runtime.h>
#include <cstdint>
#include <cstddef>

// ---------------------------------------------------------------------------
// Shapes: x (2,8,96,96,192) fp32 ; windows 1x8x8 ; NH=2 ; hd=96 ; L=512 ; MLP 768
// tokens N = 147456 ; Bp = 288 ; Dn = 8
// ---------------------------------------------------------------------------

typedef float   f32x4  __attribute__((ext_vector_type(4)));
typedef __bf16  bf16x8 __attribute__((ext_vector_type(8)));
typedef unsigned int   u32x4  __attribute__((ext_vector_type(4)));
typedef unsigned short u16x4  __attribute__((ext_vector_type(4)));

#define DEVI __device__ __forceinline__

DEVI float bf2f(unsigned short u) {
    union { unsigned int i; float f; } v; v.i = ((unsigned int)u) << 16; return v.f;
}
DEVI unsigned short f2bf(float f) {
    unsigned int u = __builtin_bit_cast(unsigned int, f);
    unsigned int r = u + 0x7fffu + ((u >> 16) & 1u);   // RNE
    return (unsigned short)(r >> 16);
}
// tanh-form GELU via one v_exp (same as round 7, passed at 0.03125)
DEVI float gelu_fast(float v) {
    float t = v * v;
    float z = v * (1.5957691216057308f + 0.07135481627f * t);
    float e = __expf(z);
    float r = 2.0f / (1.0f + e);
    return v - 0.5f * v * r;
}

// async global->LDS, 16B per lane; LDS dest is wave-uniform base + lane*16
typedef __attribute__((address_space(3))) unsigned char       lds_u8;
typedef __attribute__((address_space(1))) const unsigned char g_u8;
DEVI void gl_lds16(const void* g, void* l) {
    __builtin_amdgcn_global_load_lds((g_u8*)g, (lds_u8*)l, 16, 0, 0);
}

// ---------------------------------------------------------------------------
// K0: convert + pad weights fp32 -> bf16, folding LN gammas:
//   wq_bf[o][c] = wqkv[o][c]*n3g[c]  (640x192, pad rows 0)
//   wo_bf       = wout               (256x192)
//   w1_bf[h][c] = wfc1[h][c]*n4g[c]  (768x192)
//   w2_bf       = wfc2               (256x768, pad rows 0)
// ---------------------------------------------------------------------------
__global__ __launch_bounds__(256) void k_wconv(const float* __restrict__ wqkv,
                                               const float* __restrict__ wout,
                                               const float* __restrict__ wfc1,
                                               const float* __restrict__ wfc2,
                                               const float* __restrict__ n3g,
                                               const float* __restrict__ n4g,
                                               unsigned short* __restrict__ oq,
                                               unsigned short* __restrict__ oo,
                                               unsigned short* __restrict__ o1,
                                               unsigned short* __restrict__ o2) {
    int i = blockIdx.x * 256 + threadIdx.x;
    if (i < 122880) {                       // [640][192]
        int r = i / 192, c = i - r * 192;
        oq[i] = (r < 576) ? f2bf(wqkv[i] * n3g[c]) : (unsigned short)0;
    } else if (i < 172032) {                // [256][192]
        int j = i - 122880; int r = j / 192;
        oo[j] = (r < 192) ? f2bf(wout[j]) : (unsigned short)0;
    } else if (i < 319488) {                // [768][192]
        int j = i - 172032; int c = j % 192;
        o1[j] = f2bf(wfc1[j] * n4g[c]);
    } else if (i < 516096) {                // [256][768]
        int j = i - 319488; int r = j / 768;
        o2[j] = (r < 192) ? f2bf(wfc2[j]) : (unsigned short)0;
    }
}

// ---------------------------------------------------------------------------
// K0b: effective biases folding LN beta through the weights:
//   beffq[o] = bqkv[o] + dot(n3b, wqkv[o])   (o < 576)
//   beff1[h] = bfc1[h] + dot(n4b, wfc1[h])   (h < 768)
// one wave per output.
// ---------------------------------------------------------------------------
__global__ __launch_bounds__(256) void k_bias(const float* __restrict__ wqkv,
                                              const float* __restrict__ bqkv,
                                              const float* __restrict__ n3b,
                                              const float* __restrict__ wfc1,
                                              const float* __restrict__ bfc1,
                                              const float* __restrict__ n4b,
                                              float* __restrict__ beffq,
                                              float* __restrict__ beff1) {
    int wid = blockIdx.x * 4 + (threadIdx.x >> 6);
    int lane = threadIdx.x & 63;
    const float* wrow; const float* bb; float base; float* dst;
    if (wid < 576) { wrow = wqkv + (size_t)wid * 192; bb = n3b; base = bqkv[wid]; dst = beffq + wid; }
    else { int h = wid - 576; wrow = wfc1 + (size_t)h * 192; bb = n4b; base = bfc1[h]; dst = beff1 + h; }
    float s = wrow[lane] * bb[lane] + wrow[lane + 64] * bb[lane + 64]
            + wrow[lane + 128] * bb[lane + 128];
#pragma unroll
    for (int off = 32; off; off >>= 1) s += __shfl_xor(s, off);
    if (lane == 0) *dst = base + s;
}

// ---------------------------------------------------------------------------
// K1: fused LN3 + window-partition + qkv GEMM.
// A-tile [128][192] reg-staged from x (window gather, fp32 exact stats),
// normalized in LDS (gamma/beta folded into wq_bf/beffq -> pure per-row
// affine). B dbuf gl_lds + counted vmcnt. Epilogue: qk packed (q scaled),
// vt (v transposed) scatter.
// ---------------------------------------------------------------------------
__global__ __launch_bounds__(256) void k_qkv(const float* __restrict__ x,
                                             const unsigned short* __restrict__ Bw,
                                             const float* __restrict__ beff,
                                             unsigned short* __restrict__ qk,
                                             unsigned short* __restrict__ vt) {
    __shared__ unsigned short As[3][128][64];    // 48 KB, per-subtile swizzle j=c^(r&7)
    __shared__ unsigned short Bs[2][128 * 64];   // 32 KB dbuf
    const int tid = threadIdx.x;
    const int nwg = gridDim.x * gridDim.y;
    const int flat = blockIdx.y * gridDim.x + blockIdx.x;
    const int swz = (flat & 7) * (nwg >> 3) + (flat >> 3);
    const int bx = swz % gridDim.x, by = swz / gridDim.x;
    const int row0 = by * 128, col0 = bx * 128;
    const int wv = tid >> 6, lane = tid & 63, lr = lane & 15, lg = lane >> 4;
    const int wr = wv >> 1, wc = wv & 1;
    const int sr = lane >> 3, sc = lane & 7;

    auto stageB = [&](int t, int buf) {
        int k0 = t * 64;
#pragma unroll
        for (int i = 0; i < 4; i++) {
            int gq = wv * 4 + i;
            int r = gq * 8 + sr;
            int j = sc ^ (r & 7);
            gl_lds16(Bw + (size_t)(col0 + r) * 192 + k0 + j * 8, &Bs[buf][gq * 512]);
        }
    };

    stageB(0, 0);
    // --- stage A from x (window gather) + exact fp32 stats + normalize ---
    {
        int ar = tid >> 1, ah = tid & 1;         // 2 threads/row, 12 chunks each
        int n = row0 + ar;
        int bp = n >> 9, l = n & 511;
        int bb = bp / 144, p = bp - bb * 144;
        int hn = p / 12, wn = p - hn * 12;
        int dn = l >> 6, t_ = l & 63;
        size_t tok = ((size_t)((bb * 8 + dn) * 96 + hn * 8 + (t_ >> 3)) * 96 + wn * 8 + (t_ & 7));
        const float* src = x + tok * 192;
        float sum = 0.f, ssq = 0.f;
#pragma unroll
        for (int ci = 0; ci < 12; ci++) {
            int c = ah * 12 + ci;
            f32x4 a = *reinterpret_cast<const f32x4*>(src + c * 8);
            f32x4 b = *reinterpret_cast<const f32x4*>(src + c * 8 + 4);
            u16x4 pa, pb;
#pragma unroll
            for (int e = 0; e < 4; e++) {
                sum += a[e] + b[e]; ssq += a[e] * a[e] + b[e] * b[e];
                pa[e] = f2bf(a[e]); pb[e] = f2bf(b[e]);
            }
            int j = (c & 7) ^ (ar & 7);
            unsigned short* dst = &As[c >> 3][ar][j * 8];
            *reinterpret_cast<u16x4*>(dst) = pa;
            *reinterpret_cast<u16x4*>(dst + 4) = pb;
        }
        sum += __shfl_xor(sum, 1); ssq += __shfl_xor(ssq, 1);
        float mu = sum * (1.f / 192.f);
        float rs = rsqrtf(ssq * (1.f / 192.f) - mu * mu + 1e-5f);
#pragma unroll
        for (int ci = 0; ci < 12; ci++) {
            int c = ah * 12 + ci;
            int j = (c & 7) ^ (ar & 7);
            unsigned short* p8 = &As[c >> 3][ar][j * 8];
            u16x4 v0 = *reinterpret_cast<u16x4*>(p8);
            u16x4 v1 = *reinterpret_cast<u16x4*>(p8 + 4);
#pragma unroll
            for (int e = 0; e < 4; e++) {
                v0[e] = f2bf((bf2f(v0[e]) - mu) * rs);
                v1[e] = f2bf((bf2f(v1[e]) - mu) * rs);
            }
            *reinterpret_cast<u16x4*>(p8) = v0;
            *reinterpret_cast<u16x4*>(p8 + 4) = v1;
        }
    }
    asm volatile("s_waitcnt lgkmcnt(0)" ::: "memory");   // normalize writes drained

    f32x4 acc[4][4] = {};
#pragma unroll
    for (int t = 0; t < 3; ++t) {
        if (t + 1 < 3) {
            stageB(t + 1, (t + 1) & 1);
            asm volatile("s_waitcnt vmcnt(4)" ::: "memory");   // B(t) landed
        } else {
            asm volatile("s_waitcnt vmcnt(0)" ::: "memory");
        }
        __builtin_amdgcn_sched_barrier(0);
        __builtin_amdgcn_s_barrier();
        __builtin_amdgcn_sched_barrier(0);
#pragma unroll
        for (int kk = 0; kk < 64; kk += 32) {
            bf16x8 af[4], bf[4];
#pragma unroll
            for (int m = 0; m < 4; m++) {
                int r = wr * 64 + m * 16 + lr;
                int j = ((kk >> 3) + lg) ^ (r & 7);
                af[m] = __builtin_bit_cast(bf16x8,
                    *reinterpret_cast<const u32x4*>(&As[t][r][j * 8]));
            }
#pragma unroll
            for (int n = 0; n < 4; n++) {
                int r = wc * 64 + n * 16 + lr;
                int j = ((kk >> 3) + lg) ^ (r & 7);
                bf[n] = __builtin_bit_cast(bf16x8,
                    *reinterpret_cast<const u32x4*>(&Bs[t & 1][r * 64 + j * 8]));
            }
#pragma unroll
            for (int m = 0; m < 4; m++)
#pragma unroll
                for (int n = 0; n < 4; n++)
                    acc[m][n] = __builtin_amdgcn_mfma_f32_16x16x32_bf16(bf[n], af[m], acc[m][n], 0, 0, 0);
        }
        __builtin_amdgcn_sched_barrier(0);
        __builtin_amdgcn_s_barrier();
        __builtin_amdgcn_sched_barrier(0);
    }

#pragma unroll
    for (int m = 0; m < 4; m++) {
        const int arow = row0 + wr * 64 + m * 16 + lr;
#pragma unroll
        for (int n = 0; n < 4; n++) {
            const int colb = col0 + wc * 64 + n * 16 + lg * 4;
            if (colb < 384) {
                f32x4 b4 = *reinterpret_cast<const f32x4*>(beff + colb);
                float sc2 = (colb < 192) ? 0.1020620726159658f : 1.f;  // 1/sqrt(96) on q
                u16x4 pk;
#pragma unroll
                for (int rr = 0; rr < 4; rr++) pk[rr] = f2bf((acc[m][n][rr] + b4[rr]) * sc2);
                *reinterpret_cast<u16x4*>(qk + (size_t)arow * 384 + colb) = pk;
            } else if (colb < 576) {
                int head = (colb >= 480) ? 1 : 0;
                int bp = arow >> 9, tok = arow & 511;
                size_t vb = ((size_t)(bp * 2 + head) * 96 + (colb - 384 - head * 96)) * 512 + tok;
#pragma unroll
                for (int rr = 0; rr < 4; rr++)
                    vt[vb + (size_t)rr * 512] = f2bf(acc[m][n][rr] + beff[colb + rr]);
            }
        }
    }
}

// ---------------------------------------------------------------------------
// K2: out_proj GEMM (128x128, dbuf + counted vmcnt, swapped-operand epilogue):
// window-reverse + x residual -> ybf bf16 (natural layout). Unchanged r7 core.
// ---------------------------------------------------------------------------
__global__ __launch_bounds__(256) void k_oproj(const unsigned short* __restrict__ A,
                                               const unsigned short* __restrict__ Bw,
                                               const float* __restrict__ bias,
                                               unsigned short* __restrict__ ybf,
                                               const float* __restrict__ res) {
    __shared__ unsigned short As[2][128 * 64];
    __shared__ unsigned short Bs[2][128 * 64];
    const int tid = threadIdx.x;
    const int nwg = gridDim.x * gridDim.y;
    const int flat = blockIdx.y * gridDim.x + blockIdx.x;
    const int swz = (flat & 7) * (nwg >> 3) + (flat >> 3);
    const int bx = swz % gridDim.x, by = swz / gridDim.x;
    const int row0 = by * 128, col0 = bx * 128;
    const int wv = tid >> 6, lane = tid & 63, lr = lane & 15, lg = lane >> 4;
    const int wr = wv >> 1, wc = wv & 1;
    const int sr = lane >> 3, sc = lane & 7;
    f32x4 acc[4][4] = {};

    auto stage = [&](int t, int buf) {
        int k0 = t * 64;
#pragma unroll
        for (int i = 0; i < 4; i++) {
            int gq = wv * 4 + i;
            int r = gq * 8 + sr;
            int j = sc ^ (r & 7);
            gl_lds16(A + (size_t)(row0 + r) * 192 + k0 + j * 8, &As[buf][gq * 512]);
        }
#pragma unroll
        for (int i = 0; i < 4; i++) {
            int gq = wv * 4 + i;
            int r = gq * 8 + sr;
            int j = sc ^ (r & 7);
            gl_lds16(Bw + (size_t)(col0 + r) * 192 + k0 + j * 8, &Bs[buf][gq * 512]);
        }
    };

    stage(0, 0);
#pragma unroll
    for (int t = 0; t < 3; ++t) {
        if (t + 1 < 3) {
            stage(t + 1, (t + 1) & 1);
            asm volatile("s_waitcnt vmcnt(8)" ::: "memory");
        } else {
            asm volatile("s_waitcnt vmcnt(0)" ::: "memory");
        }
        __builtin_amdgcn_sched_barrier(0);
        __builtin_amdgcn_s_barrier();
        __builtin_amdgcn_sched_barrier(0);
#pragma unroll
        for (int kk = 0; kk < 64; kk += 32) {
            bf16x8 af[4], bf[4];
#pragma unroll
            for (int m = 0; m < 4; m++) {
                int r = wr * 64 + m * 16 + lr;
                int j = ((kk >> 3) + lg) ^ (r & 7);
                af[m] = __builtin_bit_cast(bf16x8,
                    *reinterpret_cast<const u32x4*>(&As[t & 1][r * 64 + j * 8]));
            }
#pragma unroll
            for (int n = 0; n < 4; n++) {
                int r = wc * 64 + n * 16 + lr;
                int j = ((kk >> 3) + lg) ^ (r & 7);
                bf[n] = __builtin_bit_cast(bf16x8,
                    *reinterpret_cast<const u32x4*>(&Bs[t & 1][r * 64 + j * 8]));
            }
#pragma unroll
            for (int m = 0; m < 4; m++)
#pragma unroll
                for (int n = 0; n < 4; n++)
                    acc[m][n] = __builtin_amdgcn_mfma_f32_16x16x32_bf16(bf[n], af[m], acc[m][n], 0, 0, 0);
        }
        __builtin_amdgcn_sched_barrier(0);
        __builtin_amdgcn_s_barrier();
        __builtin_amdgcn_sched_barrier(0);
    }

#pragma unroll
    for (int m = 0; m < 4; m++) {
        const int arow = row0 + wr * 64 + m * 16 + lr;
        int bp = arow >> 9, l = arow & 511;
        int bb = bp / 144, p = bp - bb * 144;
        int hn = p / 12, wn = p - hn * 12;
        int dn = l >> 6, t_ = l & 63;
        size_t tok = ((size_t)((bb * 8 + dn) * 96 + hn * 8 + (t_ >> 3)) * 96 + wn * 8 + (t_ & 7));
#pragma unroll
        for (int n = 0; n < 4; n++) {
            const int colb = col0 + wc * 64 + n * 16 + lg * 4;
            if (colb < 192) {
                size_t idx = tok * 192 + colb;
                f32x4 r4 = *reinterpret_cast<const f32x4*>(res + idx);
                f32x4 b4 = *reinterpret_cast<const f32x4*>(bias + colb);
                u16x4 pk;
#pragma unroll
                for (int rr = 0; rr < 4; rr++) pk[rr] = f2bf(r4[rr] + acc[m][n][rr] + b4[rr]);
                *reinterpret_cast<u16x4*>(ybf + idx) = pk;
            }
        }
    }
}

// ---------------------------------------------------------------------------
// K3: block-causal attention (unchanged from round 7).
// ---------------------------------------------------------------------------
__global__ __launch_bounds__(512) void k_attn(const unsigned short* __restrict__ qk,
                                              const unsigned short* __restrict__ vt,
                                              unsigned short* __restrict__ aout) {
    __shared__ unsigned short Ks[64][104];
    __shared__ unsigned short Vs[96][72];
    __shared__ unsigned short Ps[8][16][72];

    int bid = (blockIdx.x & 7) * 288 + (blockIdx.x >> 3);
    int bp = bid >> 3, rest = bid & 7, head = rest >> 2, pr = rest & 3;
    int tid = threadIdx.x, wv = tid >> 6, lane = tid & 63;
    int lr = lane & 15, lg = lane >> 4;
    int wq = wv & 3, wt = wv >> 2;
    int nk = 2 * pr + 2;

    size_t qrow0 = (size_t)bp * 512 + (size_t)(2 * pr + wt) * 64;
    const unsigned short* vbase = vt + (size_t)(bp * 2 + head) * 96 * 512;
    size_t krowb = (size_t)bp * 512;

    bf16x8 qf[3];
    {
        const unsigned short* qp = qk + (qrow0 + wq * 16 + lr) * 384 + head * 96 + lg * 8;
#pragma unroll
        for (int ks = 0; ks < 3; ks++)
            qf[ks] = __builtin_bit_cast(bf16x8, *reinterpret_cast<const u32x4*>(qp + ks * 32));
    }

    f32x4 o[6] = {};
    float m_ = -1e30f, lsum = 0.f;

    u32x4 sreg[3];
    auto issue = [&](int dnk) {
#pragma unroll
        for (int i = 0; i < 3; i++) {
            int c = tid + i * 512;
            if (c < 768) {
                int r = c / 12, cc = c - r * 12;
                sreg[i] = *reinterpret_cast<const u32x4*>(
                    qk + (krowb + dnk * 64 + r) * 384 + 192 + head * 96 + cc * 8);
            } else {
                int c2 = c - 768; int d = c2 >> 3, tb = c2 & 7;
                sreg[i] = *reinterpret_cast<const u32x4*>(
                    vbase + (size_t)d * 512 + dnk * 64 + tb * 8);
            }
        }
    };
    auto commit = [&]() {
#pragma unroll
        for (int i = 0; i < 3; i++) {
            int c = tid + i * 512;
            if (c < 768) {
                int r = c / 12, cc = c - r * 12;
                *reinterpret_cast<u32x4*>(&Ks[r][cc * 8]) = sreg[i];
            } else {
                int c2 = c - 768; int d = c2 >> 3, tb = c2 & 7;
                *reinterpret_cast<u32x4*>(&Vs[d][tb * 8]) = sreg[i];
            }
        }
    };

    issue(0);
    for (int dnk = 0; dnk < nk; ++dnk) {
        commit();
        __syncthreads();
        if (dnk + 1 < nk) issue(dnk + 1);
        if (wt == 1 || dnk < nk - 1) {
            f32x4 st[4] = {};
#pragma unroll
            for (int ks = 0; ks < 3; ks++) {
#pragma unroll
                for (int ct = 0; ct < 4; ct++) {
                    bf16x8 kf = __builtin_bit_cast(bf16x8,
                        *reinterpret_cast<const u32x4*>(&Ks[ct * 16 + lr][ks * 32 + lg * 8]));
                    st[ct] = __builtin_amdgcn_mfma_f32_16x16x32_bf16(kf, qf[ks], st[ct], 0, 0, 0);
                }
            }
            float mx = st[0][0];
#pragma unroll
            for (int ct = 0; ct < 4; ct++)
#pragma unroll
                for (int rr = 0; rr < 4; rr++) mx = fmaxf(mx, st[ct][rr]);
            mx = fmaxf(mx, __shfl_xor(mx, 16));
            mx = fmaxf(mx, __shfl_xor(mx, 32));
            float mnew = fmaxf(m_, mx);
            float corr = __expf(m_ - mnew);
            m_ = mnew;
            float ps = 0.f;
#pragma unroll
            for (int ct = 0; ct < 4; ct++) {
                u16x4 pk;
#pragma unroll
                for (int rr = 0; rr < 4; rr++) {
                    float pv = __expf(st[ct][rr] - mnew);
                    ps += pv;
                    pk[rr] = f2bf(pv);
                }
                *reinterpret_cast<u16x4*>(&Ps[wv][lr][ct * 16 + lg * 4]) = pk;
            }
            ps += __shfl_xor(ps, 16);
            ps += __shfl_xor(ps, 32);
            lsum = lsum * corr + ps;
#pragma unroll
            for (int rr = 0; rr < 4; rr++) {
                float cr = __shfl(corr, (lane & 48) | (lg * 4 + rr));
#pragma unroll
                for (int nf = 0; nf < 6; nf++) o[nf][rr] *= cr;
            }
#pragma unroll
            for (int kk = 0; kk < 2; kk++) {
                bf16x8 pf = __builtin_bit_cast(bf16x8,
                    *reinterpret_cast<const u32x4*>(&Ps[wv][lr][kk * 32 + lg * 8]));
#pragma unroll
                for (int nf = 0; nf < 6; nf++) {
                    bf16x8 vf = __builtin_bit_cast(bf16x8,
                        *reinterpret_cast<const u32x4*>(&Vs[nf * 16 + lr][kk * 32 + lg * 8]));
                    o[nf] = __builtin_amdgcn_mfma_f32_16x16x32_bf16(pf, vf, o[nf], 0, 0, 0);
                }
            }
        }
        __syncthreads();
    }

#pragma unroll
    for (int rr = 0; rr < 4; rr++) {
        float li = __shfl(lsum, (lane & 48) | (lg * 4 + rr));
        float inv = 1.f / li;
        size_t row = qrow0 + wq * 16 + lg * 4 + rr;
#pragma unroll
        for (int nf = 0; nf < 6; nf++)
            aout[row * 192 + head * 96 + nf * 16 + lr] = f2bf(o[nf][rr] * inv);
    }
}

// ---------------------------------------------------------------------------
// K4: FULLY-FUSED MLP: LN4 + fc1 + gelu + fc2 + residual, per 64-token tile.
// 512 thr (8 waves): wave (wr = w&3: 16-row group, wc = w>>2: col half).
// LDS: XN[3][64][64] (ybf tile, LN'd in place) + Hs[4][16][776] (hidden,
// per-row-group private) + Ws[2][128*64] (weight-tile dbuf ring).
// 42 weight tiles: 18 = W1 (cb 0..5 x ks 0..2), 24 = W2 (oh 0..1 x kt 0..11),
// streamed from L2 via gl_lds + counted vmcnt(2). hidden NEVER touches HBM.
// ---------------------------------------------------------------------------
__global__ __launch_bounds__(512) void k_mlp(const unsigned short* __restrict__ ybf,
                                             const unsigned short* __restrict__ w1,
                                             const unsigned short* __restrict__ w2,
                                             const float* __restrict__ beff1,
                                             const float* __restrict__ b2,
                                             float* __restrict__ out) {
    __shared__ unsigned short XN[3][64][64];     // 24 KB
    __shared__ unsigned short Hs[4][16][776];    // 97 KB  (97-chunk stride: conflict-light)
    __shared__ unsigned short Ws[2][128 * 64];   // 32 KB
    const int tid = threadIdx.x;
    const int bid = (blockIdx.x & 7) * 288 + (blockIdx.x >> 3);   // 2304 % 8 == 0
    const int row0 = bid * 64;
    const int wv = tid >> 6, lane = tid & 63, lr = lane & 15, lg = lane >> 4;
    const int wr = wv & 3, wc = wv >> 2;

    // ---- stage ybf[64][192] -> XN (3 subtiles, swizzled source) ----
#pragma unroll
    for (int i = 0; i < 3; i++) {
        int g = wv * 3 + i;                       // 0..23 1KB-groups
        int sub = g >> 3, rg = g & 7;
        int r = rg * 8 + (lane >> 3);
        int c = (lane & 7) ^ (r & 7);
        gl_lds16(ybf + (size_t)(row0 + r) * 192 + sub * 64 + c * 8, &XN[sub][rg * 8][0]);
    }
    auto stageW = [&](int tile, int buf) {
        const unsigned short* src; int ldk, rbase, kbase;
        if (tile < 18) { int cb = tile / 3, ks = tile - cb * 3; src = w1; ldk = 192; rbase = cb * 128; kbase = ks * 64; }
        else { int i2 = tile - 18; int oh = i2 / 12, kt = i2 - oh * 12; src = w2; ldk = 768; rbase = oh * 128; kbase = kt * 64; }
#pragma unroll
        for (int i = 0; i < 2; i++) {
            int g = wv * 2 + i;                   // 0..15
            int r = g * 8 + (lane >> 3);
            int c = (lane & 7) ^ (r & 7);
            gl_lds16(src + (size_t)(rbase + r) * ldk + kbase + c * 8, &Ws[buf][g * 512]);
        }
    };
    stageW(0, 0);
    asm volatile("s_waitcnt vmcnt(2)" ::: "memory");   // XN landed (3 oldest of 5)
    __builtin_amdgcn_sched_barrier(0);
    __builtin_amdgcn_s_barrier();
    __builtin_amdgcn_sched_barrier(0);

    // ---- LN4: 8 threads/row, 3 chunks each; stats then normalize in place ----
    {
        int r = tid >> 3, q = tid & 7;
        float sum = 0.f, ssq = 0.f;
        u16x4 vv[3][2];
#pragma unroll
        for (int ci = 0; ci < 3; ci++) {
            int c = q * 3 + ci;
            int j = (c & 7) ^ (r & 7);
            unsigned short* p8 = &XN[c >> 3][r][j * 8];
            vv[ci][0] = *reinterpret_cast<u16x4*>(p8);
            vv[ci][1] = *reinterpret_cast<u16x4*>(p8 + 4);
#pragma unroll
            for (int e = 0; e < 4; e++) {
                float a = bf2f(vv[ci][0][e]), b = bf2f(vv[ci][1][e]);
                sum += a + b; ssq += a * a + b * b;
            }
        }
        sum += __shfl_xor(sum, 1); ssq += __shfl_xor(ssq, 1);
        sum += __shfl_xor(sum, 2); ssq += __shfl_xor(ssq, 2);
        sum += __shfl_xor(sum, 4); ssq += __shfl_xor(ssq, 4);
        float mu = sum * (1.f / 192.f);
        float rs = rsqrtf(ssq * (1.f / 192.f) - mu * mu + 1e-5f);
#pragma unroll
        for (int ci = 0; ci < 3; ci++) {
            int c = q * 3 + ci;
            int j = (c & 7) ^ (r & 7);
            unsigned short* p8 = &XN[c >> 3][r][j * 8];
            u16x4 o0, o1;
#pragma unroll
            for (int e = 0; e < 4; e++) {
                o0[e] = f2bf((bf2f(vv[ci][0][e]) - mu) * rs);
                o1[e] = f2bf((bf2f(vv[ci][1][e]) - mu) * rs);
            }
            *reinterpret_cast<u16x4*>(p8) = o0;
            *reinterpret_cast<u16x4*>(p8 + 4) = o1;
        }
    }
    asm volatile("s_waitcnt lgkmcnt(0)" ::: "memory");

    // ---- 42-tile loop ----
    const f32x4 zf = {0.f, 0.f, 0.f, 0.f};
    f32x4 acc[4];
    acc[0] = zf; acc[1] = zf; acc[2] = zf; acc[3] = zf;
    for (int tile = 0; tile < 42; ++tile) {
        int buf = tile & 1;
        if (tile + 1 < 42) {
            stageW(tile + 1, buf ^ 1);
            asm volatile("s_waitcnt vmcnt(2)" ::: "memory");   // W(tile) landed
        } else {
            asm volatile("s_waitcnt vmcnt(0)" ::: "memory");
        }
        __builtin_amdgcn_sched_barrier(0);
        __builtin_amdgcn_s_barrier();
        __builtin_amdgcn_sched_barrier(0);

        if (tile < 18) {
            int cb = tile / 3, ks = tile - cb * 3;
            if (ks == 0) { acc[0] = zf; acc[1] = zf; acc[2] = zf; acc[3] = zf; }
            int rA = wr * 16 + lr;
#pragma unroll
            for (int kk = 0; kk < 2; kk++) {
                bf16x8 af = __builtin_bit_cast(bf16x8, *reinterpret_cast<const u32x4*>(
                    &XN[ks][rA][((kk * 4 + lg) ^ (rA & 7)) * 8]));
#pragma unroll
                for (int n = 0; n < 4; n++) {
                    int rw = wc * 64 + n * 16 + lr;
                    int j = (kk * 4 + lg) ^ (rw & 7);
                    bf16x8 bw = __builtin_bit_cast(bf16x8,
                        *reinterpret_cast<const u32x4*>(&Ws[buf][rw * 64 + j * 8]));
                    acc[n] = __builtin_amdgcn_mfma_f32_16x16x32_bf16(bw, af, acc[n], 0, 0, 0);
                }
            }
            if (ks == 2) {
#pragma unroll
                for (int n = 0; n < 4; n++) {
                    int hc = cb * 128 + wc * 64 + n * 16 + lg * 4;
                    f32x4 b4 = *reinterpret_cast<const f32x4*>(beff1 + hc);
                    u16x4 pk;
#pragma unroll
                    for (int rr = 0; rr < 4; rr++) pk[rr] = f2bf(gelu_fast(acc[n][rr] + b4[rr]));
                    *reinterpret_cast<u16x4*>(&Hs[wr][lr][hc]) = pk;
                }
            }
        } else {
            int i2 = tile - 18; int oh = i2 / 12, kt = i2 - oh * 12;
            if (kt == 0) { acc[0] = zf; acc[1] = zf; acc[2] = zf; acc[3] = zf; }
#pragma unroll
            for (int kk = 0; kk < 2; kk++) {
                bf16x8 af = __builtin_bit_cast(bf16x8, *reinterpret_cast<const u32x4*>(
                    &Hs[wr][lr][kt * 64 + kk * 32 + lg * 8]));
#pragma unroll
                for (int n = 0; n < 4; n++) {
                    int rw = wc * 64 + n * 16 + lr;
                    int j = (kk * 4 + lg) ^ (rw & 7);
                    bf16x8 bw = __builtin_bit_cast(bf16x8,
                        *reinterpret_cast<const u32x4*>(&Ws[buf][rw * 64 + j * 8]));
                    acc[n] = __builtin_amdgcn_mfma_f32_16x16x32_bf16(bw, af, acc[n], 0, 0, 0);
                }
            }
            if (kt == 11) {
                int arow = row0 + wr * 16 + lr;
#pragma unroll
                for (int n = 0; n < 4; n++) {
                    int oc = oh * 128 + wc * 64 + n * 16 + lg * 4;
                    if (oc < 192) {
                        f32x4 b4 = *reinterpret_cast<const f32x4*>(b2 + oc);
                        u16x4 rb = *reinterpret_cast<const u16x4*>(ybf + (size_t)arow * 192 + oc);
                        f32x4 o4;
#pragma unroll
                        for (int rr = 0; rr < 4; rr++) o4[rr] = bf2f(rb[rr]) + acc[n][rr] + b4[rr];
                        *reinterpret_cast<f32x4*>(out + (size_t)arow * 192 + oc) = o4;
                    }
                }
            }
        }
        // drain ds (Hs writes must be visible cross-wave) + protect Ws restage
        asm volatile("s_waitcnt lgkmcnt(0)" ::: "memory");
        __builtin_amdgcn_sched_barrier(0);
        __builtin_amdgcn_s_barrier();
        __builtin_amdgcn_sched_barrier(0);
    }
}

// ---------------------------------------------------------------------------
// Launcher. ws arena (~284.2 MB):
//   [0, 113.2M)        qk bf16 [147456][384]
//   [113.2M, 169.9M)   vt bf16 [576][96][512]
//   [169.9M, 226.5M)   attn bf16
//   [226.5M, 283.1M)   ybf bf16
//   [283.1M, 284.2M)   bf16 weights (gamma-folded) + beffq/beff1 fp32
// d_out written only by k_mlp (fully rewritten each call => replay safe).
// ---------------------------------------------------------------------------
extern "C" void kernel_launch(void* const* d_in, const int* in_sizes, int n_in,
                              void* d_out, int out_size, void* d_ws, size_t ws_size,
                              hipStream_t stream) {
    const float* x    = (const float*)d_in[0];
    const float* n3g  = (const float*)d_in[1];
    const float* n3b  = (const float*)d_in[2];
    const float* wqkv = (const float*)d_in[3];
    const float* bqkv = (const float*)d_in[4];
    const float* wout = (const float*)d_in[5];
    const float* bout = (const float*)d_in[6];
    const float* n4g  = (const float*)d_in[7];
    const float* n4b  = (const float*)d_in[8];
    const float* wfc1 = (const float*)d_in[9];
    const float* bfc1 = (const float*)d_in[10];
    const float* wfc2 = (const float*)d_in[11];
    const float* bfc2 = (const float*)d_in[12];
    float* out = (float*)d_out;

    char* ws = (char*)d_ws;
    unsigned short* qk    = (unsigned short*)(ws + 0);
    unsigned short* vt    = (unsigned short*)(ws + 113246208);
    unsigned short* attn  = (unsigned short*)(ws + 169869312);
    unsigned short* ybf   = (unsigned short*)(ws + 226492416);
    unsigned short* wq_bf = (unsigned short*)(ws + 283115520);
    unsigned short* wo_bf = (unsigned short*)(ws + 283361280);
    unsigned short* w1_bf = (unsigned short*)(ws + 283459584);
    unsigned short* w2_bf = (unsigned short*)(ws + 283754496);
    float*          beffq = (float*)(ws + 284147712);
    float*          beff1 = (float*)(ws + 284150016);

    k_wconv<<<2016, 256, 0, stream>>>(wqkv, wout, wfc1, wfc2, n3g, n4g, wq_bf, wo_bf, w1_bf, w2_bf);
    k_bias<<<336, 256, 0, stream>>>(wqkv, bqkv, n3b, wfc1, bfc1, n4b, beffq, beff1);
    k_qkv<<<dim3(5, 1152), 256, 0, stream>>>(x, wq_bf, beffq, qk, vt);
    k_attn<<<2304, 512, 0, stream>>>(qk, vt, attn);
    k_oproj<<<dim3(2, 1152), 256, 0, stream>>>(attn, wo_bf, bout, ybf, x);
    k_mlp<<<2304, 512, 0, stream>>>(ybf, w1_bf, w2_bf, beff1, bfc2, out);
}

// Round 9
// 644.308 us; speedup vs baseline: 1.1604x; 1.1604x over previous
//
#include <hip/hip_runtime.h>
#include <cstdint>
#include <cstddef>

// ---------------------------------------------------------------------------
// Shapes: x (2,8,96,96,192) fp32 ; windows 1x8x8 ; NH=2 ; hd=96 ; L=512 ; MLP 768
// tokens N = 147456 ; Bp = 288 ; Dn = 8
// ---------------------------------------------------------------------------

typedef float   f32x4  __attribute__((ext_vector_type(4)));
typedef __bf16  bf16x8 __attribute__((ext_vector_type(8)));
typedef unsigned int   u32x4  __attribute__((ext_vector_type(4)));
typedef unsigned short u16x4  __attribute__((ext_vector_type(4)));

#define DEVI __device__ __forceinline__

DEVI float bf2f(unsigned short u) {
    union { unsigned int i; float f; } v; v.i = ((unsigned int)u) << 16; return v.f;
}
DEVI unsigned short f2bf(float f) {
    unsigned int u = __builtin_bit_cast(unsigned int, f);
    unsigned int r = u + 0x7fffu + ((u >> 16) & 1u);   // RNE
    return (unsigned short)(r >> 16);
}
// tanh-form GELU via one v_exp (passed at 0.03125 since round 7)
DEVI float gelu_fast(float v) {
    float t = v * v;
    float z = v * (1.5957691216057308f + 0.07135481627f * t);
    float e = __expf(z);
    float r = 2.0f / (1.0f + e);
    return v - 0.5f * v * r;
}

// async global->LDS, 16B per lane; LDS dest is wave-uniform base + lane*16
typedef __attribute__((address_space(3))) unsigned char       lds_u8;
typedef __attribute__((address_space(1))) const unsigned char g_u8;
DEVI void gl_lds16(const void* g, void* l) {
    __builtin_amdgcn_global_load_lds((g_u8*)g, (lds_u8*)l, 16, 0, 0);
}

// ---------------------------------------------------------------------------
// K0: convert + pad weights fp32 -> bf16, folding LN gammas.
// ---------------------------------------------------------------------------
__global__ __launch_bounds__(256) void k_wconv(const float* __restrict__ wqkv,
                                               const float* __restrict__ wout,
                                               const float* __restrict__ wfc1,
                                               const float* __restrict__ wfc2,
                                               const float* __restrict__ n3g,
                                               const float* __restrict__ n4g,
                                               unsigned short* __restrict__ oq,
                                               unsigned short* __restrict__ oo,
                                               unsigned short* __restrict__ o1,
                                               unsigned short* __restrict__ o2) {
    int i = blockIdx.x * 256 + threadIdx.x;
    if (i < 122880) {                       // [640][192]
        int r = i / 192, c = i - r * 192;
        oq[i] = (r < 576) ? f2bf(wqkv[i] * n3g[c]) : (unsigned short)0;
    } else if (i < 172032) {                // [256][192]
        int j = i - 122880; int r = j / 192;
        oo[j] = (r < 192) ? f2bf(wout[j]) : (unsigned short)0;
    } else if (i < 319488) {                // [768][192]
        int j = i - 172032; int c = j % 192;
        o1[j] = f2bf(wfc1[j] * n4g[c]);
    } else if (i < 516096) {                // [256][768]
        int j = i - 319488; int r = j / 768;
        o2[j] = (r < 192) ? f2bf(wfc2[j]) : (unsigned short)0;
    }
}

// ---------------------------------------------------------------------------
// K0b: effective biases folding LN beta through the weights.
// ---------------------------------------------------------------------------
__global__ __launch_bounds__(256) void k_bias(const float* __restrict__ wqkv,
                                              const float* __restrict__ bqkv,
                                              const float* __restrict__ n3b,
                                              const float* __restrict__ wfc1,
                                              const float* __restrict__ bfc1,
                                              const float* __restrict__ n4b,
                                              float* __restrict__ beffq,
                                              float* __restrict__ beff1) {
    int wid = blockIdx.x * 4 + (threadIdx.x >> 6);
    int lane = threadIdx.x & 63;
    const float* wrow; const float* bb; float base; float* dst;
    if (wid < 576) { wrow = wqkv + (size_t)wid * 192; bb = n3b; base = bqkv[wid]; dst = beffq + wid; }
    else { int h = wid - 576; wrow = wfc1 + (size_t)h * 192; bb = n4b; base = bfc1[h]; dst = beff1 + h; }
    float s = wrow[lane] * bb[lane] + wrow[lane + 64] * bb[lane + 64]
            + wrow[lane + 128] * bb[lane + 128];
#pragma unroll
    for (int off = 32; off; off >>= 1) s += __shfl_xor(s, off);
    if (lane == 0) *dst = base + s;
}

// ---------------------------------------------------------------------------
// K1: fused LN3 + window-partition + qkv GEMM (unchanged from round 8).
// ---------------------------------------------------------------------------
__global__ __launch_bounds__(256) void k_qkv(const float* __restrict__ x,
                                             const unsigned short* __restrict__ Bw,
                                             const float* __restrict__ beff,
                                             unsigned short* __restrict__ qk,
                                             unsigned short* __restrict__ vt) {
    __shared__ unsigned short As[3][128][64];    // 48 KB, per-subtile swizzle j=c^(r&7)
    __shared__ unsigned short Bs[2][128 * 64];   // 32 KB dbuf
    const int tid = threadIdx.x;
    const int nwg = gridDim.x * gridDim.y;
    const int flat = blockIdx.y * gridDim.x + blockIdx.x;
    const int swz = (flat & 7) * (nwg >> 3) + (flat >> 3);
    const int bx = swz % gridDim.x, by = swz / gridDim.x;
    const int row0 = by * 128, col0 = bx * 128;
    const int wv = tid >> 6, lane = tid & 63, lr = lane & 15, lg = lane >> 4;
    const int wr = wv >> 1, wc = wv & 1;
    const int sr = lane >> 3, sc = lane & 7;

    auto stageB = [&](int t, int buf) {
        int k0 = t * 64;
#pragma unroll
        for (int i = 0; i < 4; i++) {
            int gq = wv * 4 + i;
            int r = gq * 8 + sr;
            int j = sc ^ (r & 7);
            gl_lds16(Bw + (size_t)(col0 + r) * 192 + k0 + j * 8, &Bs[buf][gq * 512]);
        }
    };

    stageB(0, 0);
    {
        int ar = tid >> 1, ah = tid & 1;         // 2 threads/row, 12 chunks each
        int n = row0 + ar;
        int bp = n >> 9, l = n & 511;
        int bb = bp / 144, p = bp - bb * 144;
        int hn = p / 12, wn = p - hn * 12;
        int dn = l >> 6, t_ = l & 63;
        size_t tok = ((size_t)((bb * 8 + dn) * 96 + hn * 8 + (t_ >> 3)) * 96 + wn * 8 + (t_ & 7));
        const float* src = x + tok * 192;
        float sum = 0.f, ssq = 0.f;
#pragma unroll
        for (int ci = 0; ci < 12; ci++) {
            int c = ah * 12 + ci;
            f32x4 a = *reinterpret_cast<const f32x4*>(src + c * 8);
            f32x4 b = *reinterpret_cast<const f32x4*>(src + c * 8 + 4);
            u16x4 pa, pb;
#pragma unroll
            for (int e = 0; e < 4; e++) {
                sum += a[e] + b[e]; ssq += a[e] * a[e] + b[e] * b[e];
                pa[e] = f2bf(a[e]); pb[e] = f2bf(b[e]);
            }
            int j = (c & 7) ^ (ar & 7);
            unsigned short* dst = &As[c >> 3][ar][j * 8];
            *reinterpret_cast<u16x4*>(dst) = pa;
            *reinterpret_cast<u16x4*>(dst + 4) = pb;
        }
        sum += __shfl_xor(sum, 1); ssq += __shfl_xor(ssq, 1);
        float mu = sum * (1.f / 192.f);
        float rs = rsqrtf(ssq * (1.f / 192.f) - mu * mu + 1e-5f);
#pragma unroll
        for (int ci = 0; ci < 12; ci++) {
            int c = ah * 12 + ci;
            int j = (c & 7) ^ (ar & 7);
            unsigned short* p8 = &As[c >> 3][ar][j * 8];
            u16x4 v0 = *reinterpret_cast<u16x4*>(p8);
            u16x4 v1 = *reinterpret_cast<u16x4*>(p8 + 4);
#pragma unroll
            for (int e = 0; e < 4; e++) {
                v0[e] = f2bf((bf2f(v0[e]) - mu) * rs);
                v1[e] = f2bf((bf2f(v1[e]) - mu) * rs);
            }
            *reinterpret_cast<u16x4*>(p8) = v0;
            *reinterpret_cast<u16x4*>(p8 + 4) = v1;
        }
    }
    asm volatile("s_waitcnt lgkmcnt(0)" ::: "memory");

    f32x4 acc[4][4] = {};
#pragma unroll
    for (int t = 0; t < 3; ++t) {
        if (t + 1 < 3) {
            stageB(t + 1, (t + 1) & 1);
            asm volatile("s_waitcnt vmcnt(4)" ::: "memory");
        } else {
            asm volatile("s_waitcnt vmcnt(0)" ::: "memory");
        }
        __builtin_amdgcn_sched_barrier(0);
        __builtin_amdgcn_s_barrier();
        __builtin_amdgcn_sched_barrier(0);
#pragma unroll
        for (int kk = 0; kk < 64; kk += 32) {
            bf16x8 af[4], bf[4];
#pragma unroll
            for (int m = 0; m < 4; m++) {
                int r = wr * 64 + m * 16 + lr;
                int j = ((kk >> 3) + lg) ^ (r & 7);
                af[m] = __builtin_bit_cast(bf16x8,
                    *reinterpret_cast<const u32x4*>(&As[t][r][j * 8]));
            }
#pragma unroll
            for (int n = 0; n < 4; n++) {
                int r = wc * 64 + n * 16 + lr;
                int j = ((kk >> 3) + lg) ^ (r & 7);
                bf[n] = __builtin_bit_cast(bf16x8,
                    *reinterpret_cast<const u32x4*>(&Bs[t & 1][r * 64 + j * 8]));
            }
#pragma unroll
            for (int m = 0; m < 4; m++)
#pragma unroll
                for (int n = 0; n < 4; n++)
                    acc[m][n] = __builtin_amdgcn_mfma_f32_16x16x32_bf16(bf[n], af[m], acc[m][n], 0, 0, 0);
        }
        __builtin_amdgcn_sched_barrier(0);
        __builtin_amdgcn_s_barrier();
        __builtin_amdgcn_sched_barrier(0);
    }

#pragma unroll
    for (int m = 0; m < 4; m++) {
        const int arow = row0 + wr * 64 + m * 16 + lr;
#pragma unroll
        for (int n = 0; n < 4; n++) {
            const int colb = col0 + wc * 64 + n * 16 + lg * 4;
            if (colb < 384) {
                f32x4 b4 = *reinterpret_cast<const f32x4*>(beff + colb);
                float sc2 = (colb < 192) ? 0.1020620726159658f : 1.f;  // 1/sqrt(96) on q
                u16x4 pk;
#pragma unroll
                for (int rr = 0; rr < 4; rr++) pk[rr] = f2bf((acc[m][n][rr] + b4[rr]) * sc2);
                *reinterpret_cast<u16x4*>(qk + (size_t)arow * 384 + colb) = pk;
            } else if (colb < 576) {
                int head = (colb >= 480) ? 1 : 0;
                int bp = arow >> 9, tok = arow & 511;
                size_t vb = ((size_t)(bp * 2 + head) * 96 + (colb - 384 - head * 96)) * 512 + tok;
#pragma unroll
                for (int rr = 0; rr < 4; rr++)
                    vt[vb + (size_t)rr * 512] = f2bf(acc[m][n][rr] + beff[colb + rr]);
            }
        }
    }
}

// ---------------------------------------------------------------------------
// K2: out_proj GEMM (unchanged from round 8).
// ---------------------------------------------------------------------------
__global__ __launch_bounds__(256) void k_oproj(const unsigned short* __restrict__ A,
                                               const unsigned short* __restrict__ Bw,
                                               const float* __restrict__ bias,
                                               unsigned short* __restrict__ ybf,
                                               const float* __restrict__ res) {
    __shared__ unsigned short As[2][128 * 64];
    __shared__ unsigned short Bs[2][128 * 64];
    const int tid = threadIdx.x;
    const int nwg = gridDim.x * gridDim.y;
    const int flat = blockIdx.y * gridDim.x + blockIdx.x;
    const int swz = (flat & 7) * (nwg >> 3) + (flat >> 3);
    const int bx = swz % gridDim.x, by = swz / gridDim.x;
    const int row0 = by * 128, col0 = bx * 128;
    const int wv = tid >> 6, lane = tid & 63, lr = lane & 15, lg = lane >> 4;
    const int wr = wv >> 1, wc = wv & 1;
    const int sr = lane >> 3, sc = lane & 7;
    f32x4 acc[4][4] = {};

    auto stage = [&](int t, int buf) {
        int k0 = t * 64;
#pragma unroll
        for (int i = 0; i < 4; i++) {
            int gq = wv * 4 + i;
            int r = gq * 8 + sr;
            int j = sc ^ (r & 7);
            gl_lds16(A + (size_t)(row0 + r) * 192 + k0 + j * 8, &As[buf][gq * 512]);
        }
#pragma unroll
        for (int i = 0; i < 4; i++) {
            int gq = wv * 4 + i;
            int r = gq * 8 + sr;
            int j = sc ^ (r & 7);
            gl_lds16(Bw + (size_t)(col0 + r) * 192 + k0 + j * 8, &Bs[buf][gq * 512]);
        }
    };

    stage(0, 0);
#pragma unroll
    for (int t = 0; t < 3; ++t) {
        if (t + 1 < 3) {
            stage(t + 1, (t + 1) & 1);
            asm volatile("s_waitcnt vmcnt(8)" ::: "memory");
        } else {
            asm volatile("s_waitcnt vmcnt(0)" ::: "memory");
        }
        __builtin_amdgcn_sched_barrier(0);
        __builtin_amdgcn_s_barrier();
        __builtin_amdgcn_sched_barrier(0);
#pragma unroll
        for (int kk = 0; kk < 64; kk += 32) {
            bf16x8 af[4], bf[4];
#pragma unroll
            for (int m = 0; m < 4; m++) {
                int r = wr * 64 + m * 16 + lr;
                int j = ((kk >> 3) + lg) ^ (r & 7);
                af[m] = __builtin_bit_cast(bf16x8,
                    *reinterpret_cast<const u32x4*>(&As[t & 1][r * 64 + j * 8]));
            }
#pragma unroll
            for (int n = 0; n < 4; n++) {
                int r = wc * 64 + n * 16 + lr;
                int j = ((kk >> 3) + lg) ^ (r & 7);
                bf[n] = __builtin_bit_cast(bf16x8,
                    *reinterpret_cast<const u32x4*>(&Bs[t & 1][r * 64 + j * 8]));
            }
#pragma unroll
            for (int m = 0; m < 4; m++)
#pragma unroll
                for (int n = 0; n < 4; n++)
                    acc[m][n] = __builtin_amdgcn_mfma_f32_16x16x32_bf16(bf[n], af[m], acc[m][n], 0, 0, 0);
        }
        __builtin_amdgcn_sched_barrier(0);
        __builtin_amdgcn_s_barrier();
        __builtin_amdgcn_sched_barrier(0);
    }

#pragma unroll
    for (int m = 0; m < 4; m++) {
        const int arow = row0 + wr * 64 + m * 16 + lr;
        int bp = arow >> 9, l = arow & 511;
        int bb = bp / 144, p = bp - bb * 144;
        int hn = p / 12, wn = p - hn * 12;
        int dn = l >> 6, t_ = l & 63;
        size_t tok = ((size_t)((bb * 8 + dn) * 96 + hn * 8 + (t_ >> 3)) * 96 + wn * 8 + (t_ & 7));
#pragma unroll
        for (int n = 0; n < 4; n++) {
            const int colb = col0 + wc * 64 + n * 16 + lg * 4;
            if (colb < 192) {
                size_t idx = tok * 192 + colb;
                f32x4 r4 = *reinterpret_cast<const f32x4*>(res + idx);
                f32x4 b4 = *reinterpret_cast<const f32x4*>(bias + colb);
                u16x4 pk;
#pragma unroll
                for (int rr = 0; rr < 4; rr++) pk[rr] = f2bf(r4[rr] + acc[m][n][rr] + b4[rr]);
                *reinterpret_cast<u16x4*>(ybf + idx) = pk;
            }
        }
    }
}

// ---------------------------------------------------------------------------
// K3: block-causal attention (unchanged).
// ---------------------------------------------------------------------------
__global__ __launch_bounds__(512) void k_attn(const unsigned short* __restrict__ qk,
                                              const unsigned short* __restrict__ vt,
                                              unsigned short* __restrict__ aout) {
    __shared__ unsigned short Ks[64][104];
    __shared__ unsigned short Vs[96][72];
    __shared__ unsigned short Ps[8][16][72];

    int bid = (blockIdx.x & 7) * 288 + (blockIdx.x >> 3);
    int bp = bid >> 3, rest = bid & 7, head = rest >> 2, pr = rest & 3;
    int tid = threadIdx.x, wv = tid >> 6, lane = tid & 63;
    int lr = lane & 15, lg = lane >> 4;
    int wq = wv & 3, wt = wv >> 2;
    int nk = 2 * pr + 2;

    size_t qrow0 = (size_t)bp * 512 + (size_t)(2 * pr + wt) * 64;
    const unsigned short* vbase = vt + (size_t)(bp * 2 + head) * 96 * 512;
    size_t krowb = (size_t)bp * 512;

    bf16x8 qf[3];
    {
        const unsigned short* qp = qk + (qrow0 + wq * 16 + lr) * 384 + head * 96 + lg * 8;
#pragma unroll
        for (int ks = 0; ks < 3; ks++)
            qf[ks] = __builtin_bit_cast(bf16x8, *reinterpret_cast<const u32x4*>(qp + ks * 32));
    }

    f32x4 o[6] = {};
    float m_ = -1e30f, lsum = 0.f;

    u32x4 sreg[3];
    auto issue = [&](int dnk) {
#pragma unroll
        for (int i = 0; i < 3; i++) {
            int c = tid + i * 512;
            if (c < 768) {
                int r = c / 12, cc = c - r * 12;
                sreg[i] = *reinterpret_cast<const u32x4*>(
                    qk + (krowb + dnk * 64 + r) * 384 + 192 + head * 96 + cc * 8);
            } else {
                int c2 = c - 768; int d = c2 >> 3, tb = c2 & 7;
                sreg[i] = *reinterpret_cast<const u32x4*>(
                    vbase + (size_t)d * 512 + dnk * 64 + tb * 8);
            }
        }
    };
    auto commit = [&]() {
#pragma unroll
        for (int i = 0; i < 3; i++) {
            int c = tid + i * 512;
            if (c < 768) {
                int r = c / 12, cc = c - r * 12;
                *reinterpret_cast<u32x4*>(&Ks[r][cc * 8]) = sreg[i];
            } else {
                int c2 = c - 768; int d = c2 >> 3, tb = c2 & 7;
                *reinterpret_cast<u32x4*>(&Vs[d][tb * 8]) = sreg[i];
            }
        }
    };

    issue(0);
    for (int dnk = 0; dnk < nk; ++dnk) {
        commit();
        __syncthreads();
        if (dnk + 1 < nk) issue(dnk + 1);
        if (wt == 1 || dnk < nk - 1) {
            f32x4 st[4] = {};
#pragma unroll
            for (int ks = 0; ks < 3; ks++) {
#pragma unroll
                for (int ct = 0; ct < 4; ct++) {
                    bf16x8 kf = __builtin_bit_cast(bf16x8,
                        *reinterpret_cast<const u32x4*>(&Ks[ct * 16 + lr][ks * 32 + lg * 8]));
                    st[ct] = __builtin_amdgcn_mfma_f32_16x16x32_bf16(kf, qf[ks], st[ct], 0, 0, 0);
                }
            }
            float mx = st[0][0];
#pragma unroll
            for (int ct = 0; ct < 4; ct++)
#pragma unroll
                for (int rr = 0; rr < 4; rr++) mx = fmaxf(mx, st[ct][rr]);
            mx = fmaxf(mx, __shfl_xor(mx, 16));
            mx = fmaxf(mx, __shfl_xor(mx, 32));
            float mnew = fmaxf(m_, mx);
            float corr = __expf(m_ - mnew);
            m_ = mnew;
            float ps = 0.f;
#pragma unroll
            for (int ct = 0; ct < 4; ct++) {
                u16x4 pk;
#pragma unroll
                for (int rr = 0; rr < 4; rr++) {
                    float pv = __expf(st[ct][rr] - mnew);
                    ps += pv;
                    pk[rr] = f2bf(pv);
                }
                *reinterpret_cast<u16x4*>(&Ps[wv][lr][ct * 16 + lg * 4]) = pk;
            }
            ps += __shfl_xor(ps, 16);
            ps += __shfl_xor(ps, 32);
            lsum = lsum * corr + ps;
#pragma unroll
            for (int rr = 0; rr < 4; rr++) {
                float cr = __shfl(corr, (lane & 48) | (lg * 4 + rr));
#pragma unroll
                for (int nf = 0; nf < 6; nf++) o[nf][rr] *= cr;
            }
#pragma unroll
            for (int kk = 0; kk < 2; kk++) {
                bf16x8 pf = __builtin_bit_cast(bf16x8,
                    *reinterpret_cast<const u32x4*>(&Ps[wv][lr][kk * 32 + lg * 8]));
#pragma unroll
                for (int nf = 0; nf < 6; nf++) {
                    bf16x8 vf = __builtin_bit_cast(bf16x8,
                        *reinterpret_cast<const u32x4*>(&Vs[nf * 16 + lr][kk * 32 + lg * 8]));
                    o[nf] = __builtin_amdgcn_mfma_f32_16x16x32_bf16(pf, vf, o[nf], 0, 0, 0);
                }
            }
        }
        __syncthreads();
    }

#pragma unroll
    for (int rr = 0; rr < 4; rr++) {
        float li = __shfl(lsum, (lane & 48) | (lg * 4 + rr));
        float inv = 1.f / li;
        size_t row = qrow0 + wq * 16 + lg * 4 + rr;
#pragma unroll
        for (int nf = 0; nf < 6; nf++)
            aout[row * 192 + head * 96 + nf * 16 + lr] = f2bf(o[nf][rr] * inv);
    }
}

// ---------------------------------------------------------------------------
// K4: fused MLP v2 — LN4 + fc1 + GELU + fc2 + residual per 64-token block.
// 256 thr (4 waves: tHalf = w&1 owns 32 tokens, oHalf = w>>1 owns h/o half).
// LDS = 80 KB exactly -> 2 WG/CU:
//   XN[3][64][64]  24 KB  post-LN activations (resident, chunk-XOR swizzled)
//   Ws1[2][3][64][64] 48 KB  W1 64-hidden slab, double-buffered (gl_lds)
//   Hs[64][64]      8 KB  hidden slab (XOR-swizzled, conflict-free)
// 12 slabs; per slab: {W2(s)->regs, wait W1(s), barrier, prefetch W1(s+1),
// fc1 24 MFMAs, gelu, H-store, wait W2+lgkm, barrier, fc2 24 MFMAs -> accO}.
// Output acc 2x6 f32x4 in VGPRs; hidden never touches HBM; 24 barriers/block.
// ---------------------------------------------------------------------------
__global__ __launch_bounds__(256) void k_mlp2(const unsigned short* __restrict__ ybf,
                                              const unsigned short* __restrict__ w1,
                                              const unsigned short* __restrict__ w2,
                                              const float* __restrict__ beff1,
                                              const float* __restrict__ b2,
                                              float* __restrict__ out) {
    __shared__ unsigned short XN[3][64][64];
    __shared__ unsigned short Ws1[2][3][64][64];
    __shared__ unsigned short Hs[64][64];
    const int tid = threadIdx.x;
    const int bid = (blockIdx.x & 7) * 288 + (blockIdx.x >> 3);   // XCD swizzle
    const int row0 = bid * 64;
    const int wv = tid >> 6, lane = tid & 63, lr = lane & 15, lg = lane >> 4;
    const int tHalf = wv & 1, oHalf = wv >> 1;

    // ---- prologue: stage ybf tile -> XN, stage W1 slab 0 ----
#pragma unroll
    for (int i = 0; i < 6; i++) {
        int g = wv * 6 + i;                       // 24 groups of 8 rows
        int sub = g >> 3, rg = g & 7;
        int r = rg * 8 + (lane >> 3);
        int c = (lane & 7) ^ (r & 7);
        gl_lds16(ybf + (size_t)(row0 + r) * 192 + sub * 64 + c * 8, &XN[sub][rg * 8][0]);
    }
    auto stageW1 = [&](int s, int buf) {
#pragma unroll
        for (int i = 0; i < 6; i++) {
            int g = wv * 6 + i;
            int sub = g >> 3, rg = g & 7;
            int r = rg * 8 + (lane >> 3);
            int c = (lane & 7) ^ (r & 7);
            gl_lds16(w1 + (size_t)(s * 64 + r) * 192 + sub * 64 + c * 8, &Ws1[buf][sub][rg * 8][0]);
        }
    };
    stageW1(0, 0);
    asm volatile("s_waitcnt vmcnt(6)" ::: "memory");   // XN landed (W1(0) in flight)
    __builtin_amdgcn_sched_barrier(0);
    __builtin_amdgcn_s_barrier();
    __builtin_amdgcn_sched_barrier(0);

    // ---- LN4 in place on XN: 4 threads/row, 6 chunks each ----
    {
        int r = tid >> 2, q = tid & 3;
        float sum = 0.f, ssq = 0.f;
        u16x4 vv[6][2];
#pragma unroll
        for (int ci = 0; ci < 6; ci++) {
            int c = q * 6 + ci;                   // 0..23
            int j = (c & 7) ^ (r & 7);
            unsigned short* p8 = &XN[c >> 3][r][j * 8];
            vv[ci][0] = *reinterpret_cast<u16x4*>(p8);
            vv[ci][1] = *reinterpret_cast<u16x4*>(p8 + 4);
#pragma unroll
            for (int e = 0; e < 4; e++) {
                float a = bf2f(vv[ci][0][e]), b = bf2f(vv[ci][1][e]);
                sum += a + b; ssq += a * a + b * b;
            }
        }
        sum += __shfl_xor(sum, 1); ssq += __shfl_xor(ssq, 1);
        sum += __shfl_xor(sum, 2); ssq += __shfl_xor(ssq, 2);
        float mu = sum * (1.f / 192.f);
        float rs = rsqrtf(ssq * (1.f / 192.f) - mu * mu + 1e-5f);
#pragma unroll
        for (int ci = 0; ci < 6; ci++) {
            int c = q * 6 + ci;
            int j = (c & 7) ^ (r & 7);
            unsigned short* p8 = &XN[c >> 3][r][j * 8];
            u16x4 o0, o1;
#pragma unroll
            for (int e = 0; e < 4; e++) {
                o0[e] = f2bf((bf2f(vv[ci][0][e]) - mu) * rs);
                o1[e] = f2bf((bf2f(vv[ci][1][e]) - mu) * rs);
            }
            *reinterpret_cast<u16x4*>(p8) = o0;
            *reinterpret_cast<u16x4*>(p8 + 4) = o1;
        }
    }
    asm volatile("s_waitcnt lgkmcnt(0)" ::: "memory");
    __builtin_amdgcn_sched_barrier(0);
    __builtin_amdgcn_s_barrier();
    __builtin_amdgcn_sched_barrier(0);

    // ---- 12-slab fc1/fc2 interleave ----
    f32x4 accO[2][6] = {};
    for (int s = 0; s < 12; ++s) {
        const int buf = s & 1;
        // W2(s) -> registers (L2-resident; 12 b128/wave)
        u32x4 w2r[6][2];
#pragma unroll
        for (int n = 0; n < 6; n++)
#pragma unroll
            for (int kk = 0; kk < 2; kk++) {
                int o = oHalf * 96 + n * 16 + lr;
                w2r[n][kk] = *reinterpret_cast<const u32x4*>(
                    w2 + (size_t)o * 768 + s * 64 + kk * 32 + lg * 8);
            }
        __builtin_amdgcn_sched_barrier(0);
        asm volatile("s_waitcnt vmcnt(12)" ::: "memory");   // W1(s) landed; W2(s) flies
        __builtin_amdgcn_sched_barrier(0);
        __builtin_amdgcn_s_barrier();                       // A: Ws1[buf] ready; H free
        __builtin_amdgcn_sched_barrier(0);
        if (s + 1 < 12) stageW1(s + 1, buf ^ 1);            // overwrite-safe after A

        // fc1: hidden slab = XN @ W1slab^T   (lane: lr=token, lg*4+rr=h)
        f32x4 acc1[2][2] = {};
#pragma unroll
        for (int kk = 0; kk < 6; kk++) {
            int sub = kk >> 1;
            bf16x8 ax[2], bw[2];
#pragma unroll
            for (int m = 0; m < 2; m++) {
                int t = tHalf * 32 + m * 16 + lr;
                int j = ((kk & 1) * 4 + lg) ^ (t & 7);
                ax[m] = __builtin_bit_cast(bf16x8,
                    *reinterpret_cast<const u32x4*>(&XN[sub][t][j * 8]));
            }
#pragma unroll
            for (int n = 0; n < 2; n++) {
                int hr = oHalf * 32 + n * 16 + lr;
                int j = ((kk & 1) * 4 + lg) ^ (hr & 7);
                bw[n] = __builtin_bit_cast(bf16x8,
                    *reinterpret_cast<const u32x4*>(&Ws1[buf][sub][hr][j * 8]));
            }
#pragma unroll
            for (int m = 0; m < 2; m++)
#pragma unroll
                for (int n = 0; n < 2; n++)
                    acc1[m][n] = __builtin_amdgcn_mfma_f32_16x16x32_bf16(bw[n], ax[m], acc1[m][n], 0, 0, 0);
        }
        // gelu + H store (chunk-XOR swizzled; conflict-free u16x4)
#pragma unroll
        for (int m = 0; m < 2; m++) {
            int t = tHalf * 32 + m * 16 + lr;
#pragma unroll
            for (int n = 0; n < 2; n++) {
                int h0 = oHalf * 32 + n * 16 + lg * 4;         // 0..63 in slab
                f32x4 b4 = *reinterpret_cast<const f32x4*>(beff1 + s * 64 + h0);
                u16x4 pk;
#pragma unroll
                for (int rr = 0; rr < 4; rr++) pk[rr] = f2bf(gelu_fast(acc1[m][n][rr] + b4[rr]));
                int jw = (h0 >> 3) ^ (t & 7);
                *reinterpret_cast<u16x4*>(&Hs[t][jw * 8 + (h0 & 7)]) = pk;
            }
        }
        if (s < 11) asm volatile("s_waitcnt vmcnt(6) lgkmcnt(0)" ::: "memory");  // W2(s) done
        else        asm volatile("s_waitcnt vmcnt(0) lgkmcnt(0)" ::: "memory");
        __builtin_amdgcn_sched_barrier(0);
        __builtin_amdgcn_s_barrier();                       // B: H visible
        __builtin_amdgcn_sched_barrier(0);

        // fc2 partial: accO += H @ W2slab^T   (lane: lr=token, lg*4+rr=o)
#pragma unroll
        for (int kk = 0; kk < 2; kk++) {
            bf16x8 ah[2];
#pragma unroll
            for (int m = 0; m < 2; m++) {
                int t = tHalf * 32 + m * 16 + lr;
                int j = (kk * 4 + lg) ^ (t & 7);
                ah[m] = __builtin_bit_cast(bf16x8,
                    *reinterpret_cast<const u32x4*>(&Hs[t][j * 8]));
            }
#pragma unroll
            for (int m = 0; m < 2; m++)
#pragma unroll
                for (int n = 0; n < 6; n++)
                    accO[m][n] = __builtin_amdgcn_mfma_f32_16x16x32_bf16(
                        __builtin_bit_cast(bf16x8, w2r[n][kk]), ah[m], accO[m][n], 0, 0, 0);
        }
    }

    // ---- epilogue: bias + ybf residual -> fp32 out (packed f32x4) ----
#pragma unroll
    for (int m = 0; m < 2; m++) {
        int t = row0 + tHalf * 32 + m * 16 + lr;
#pragma unroll
        for (int n = 0; n < 6; n++) {
            int o0 = oHalf * 96 + n * 16 + lg * 4;
            f32x4 b4 = *reinterpret_cast<const f32x4*>(b2 + o0);
            u16x4 rb = *reinterpret_cast<const u16x4*>(ybf + (size_t)t * 192 + o0);
            f32x4 o4;
#pragma unroll
            for (int rr = 0; rr < 4; rr++) o4[rr] = bf2f(rb[rr]) + accO[m][n][rr] + b4[rr];
            *reinterpret_cast<f32x4*>(out + (size_t)t * 192 + o0) = o4;
        }
    }
}

// ---------------------------------------------------------------------------
// Launcher. ws arena (~284.2 MB):
//   [0, 113.2M)        qk bf16 [147456][384]
//   [113.2M, 169.9M)   vt bf16 [576][96][512]
//   [169.9M, 226.5M)   attn bf16
//   [226.5M, 283.1M)   ybf bf16
//   [283.1M, 284.2M)   bf16 weights (gamma-folded) + beffq/beff1 fp32
// d_out written only by k_mlp2 (fully rewritten each call => replay safe).
// ---------------------------------------------------------------------------
extern "C" void kernel_launch(void* const* d_in, const int* in_sizes, int n_in,
                              void* d_out, int out_size, void* d_ws, size_t ws_size,
                              hipStream_t stream) {
    const float* x    = (const float*)d_in[0];
    const float* n3g  = (const float*)d_in[1];
    const float* n3b  = (const float*)d_in[2];
    const float* wqkv = (const float*)d_in[3];
    const float* bqkv = (const float*)d_in[4];
    const float* wout = (const float*)d_in[5];
    const float* bout = (const float*)d_in[6];
    const float* n4g  = (const float*)d_in[7];
    const float* n4b  = (const float*)d_in[8];
    const float* wfc1 = (const float*)d_in[9];
    const float* bfc1 = (const float*)d_in[10];
    const float* wfc2 = (const float*)d_in[11];
    const float* bfc2 = (const float*)d_in[12];
    float* out = (float*)d_out;

    char* ws = (char*)d_ws;
    unsigned short* qk    = (unsigned short*)(ws + 0);
    unsigned short* vt    = (unsigned short*)(ws + 113246208);
    unsigned short* attn  = (unsigned short*)(ws + 169869312);
    unsigned short* ybf   = (unsigned short*)(ws + 226492416);
    unsigned short* wq_bf = (unsigned short*)(ws + 283115520);
    unsigned short* wo_bf = (unsigned short*)(ws + 283361280);
    unsigned short* w1_bf = (unsigned short*)(ws + 283459584);
    unsigned short* w2_bf = (unsigned short*)(ws + 283754496);
    float*          beffq = (float*)(ws + 284147712);
    float*          beff1 = (float*)(ws + 284150016);

    k_wconv<<<2016, 256, 0, stream>>>(wqkv, wout, wfc1, wfc2, n3g, n4g, wq_bf, wo_bf, w1_bf, w2_bf);
    k_bias<<<336, 256, 0, stream>>>(wqkv, bqkv, n3b, wfc1, bfc1, n4b, beffq, beff1);
    k_qkv<<<dim3(5, 1152), 256, 0, stream>>>(x, wq_bf, beffq, qk, vt);
    k_attn<<<2304, 512, 0, stream>>>(qk, vt, attn);
    k_oproj<<<dim3(2, 1152), 256, 0, stream>>>(attn, wo_bf, bout, ybf, x);
    k_mlp2<<<2304, 256, 0, stream>>>(ybf, w1_bf, w2_bf, beff1, bfc2, out);
}